// Round 3
// baseline (192.244 us; speedup 1.0000x reference)
//
#include <hip/hip_runtime.h>

// YOLO layer decode, MI355X. R3: float4-per-lane (4 s-positions per thread),
// classes processed in chunks of 16 channels; each chunk ends with each lane
// writing one FULL 64B conf line per position (4 back-to-back float4 stores),
// so no partial-line write amplification and 4x bytes/request vs R2.

#define NCLS 80
#define NA   3
#define BB   32
#define WW   76
#define HH   76
#define WH   (WW*HH)          // 5776
#define PP   (WH*NA)          // 17328
#define SQ   (WH/4)           // 1444 quads per (b,a)
#define CHUNK 16

__global__ __launch_bounds__(256, 4) void yolo_decode_kernel(
    const float* __restrict__ in,       // (B, 255, W, H)
    const float* __restrict__ anchors,  // (2, 3) flat: [d*3 + a]
    float* __restrict__ boxes,          // (B, P, 4)
    float* __restrict__ conf,           // (B, P, 80)
    float* __restrict__ scores)         // (B, P)
{
    int idx = blockIdx.x * 256 + threadIdx.x;   // idx = (b*NA + a)*SQ + q
    const int total = BB * NA * SQ;             // 138,624
    if (idx >= total) return;

    int q  = idx % SQ;
    int ba = idx / SQ;
    int a  = ba % NA;
    int b  = ba / NA;
    int s0 = q * 4;                             // 4 consecutive s positions

    const float* base = in + (size_t)(b * 255 + a * 85) * WH + s0;

    // ---- head: 5 float4 loads ----
    float4 txv = *reinterpret_cast<const float4*>(base + (size_t)0 * WH);
    float4 tyv = *reinterpret_cast<const float4*>(base + (size_t)1 * WH);
    float4 twv = *reinterpret_cast<const float4*>(base + (size_t)2 * WH);
    float4 thv = *reinterpret_cast<const float4*>(base + (size_t)3 * WH);
    float4 tov = *reinterpret_cast<const float4*>(base + (size_t)4 * WH);

    float aw = anchors[a];
    float ah = anchors[3 + a];

    float so[4], smax[4];
    const float* tx = &txv.x; const float* ty = &tyv.x;
    const float* tw = &twv.x; const float* th = &thv.x;
    const float* to = &tov.x;

    #pragma unroll
    for (int k = 0; k < 4; ++k) {
        int s = s0 + k;
        int w = s / HH;
        int h = s - w * HH;
        float sx = 1.0f / (1.0f + __expf(-tx[k]));
        float sy = 1.0f / (1.0f + __expf(-ty[k]));
        float bx = (sx + (float)w) * (1.0f / WW);
        float by = (sy + (float)h) * (1.0f / HH);
        float bw = __expf(tw[k]) * aw;
        float bh = __expf(th[k]) * ah;
        int p = s * 3 + a;
        float4 box = make_float4(bx - 0.5f * bw, by - 0.5f * bh,
                                 bx + 0.5f * bw, by + 0.5f * bh);
        *reinterpret_cast<float4*>(boxes + (size_t)(b * PP + p) * 4) = box;
        so[k]   = 1.0f / (1.0f + __expf(-to[k]));
        smax[k] = 0.0f;
    }

    // ---- conf: 5 chunks of 16 channels ----
    float* crow = conf + ((size_t)b * PP + (size_t)s0 * 3 + a) * NCLS;

    #pragma unroll
    for (int c0 = 0; c0 < NCLS; c0 += CHUNK) {
        float4 v[CHUNK];
        #pragma unroll
        for (int j = 0; j < CHUNK; ++j)
            v[j] = *reinterpret_cast<const float4*>(base + (size_t)(5 + c0 + j) * WH);

        #pragma unroll
        for (int j = 0; j < CHUNK; ++j) {
            float* e = &v[j].x;
            #pragma unroll
            for (int k = 0; k < 4; ++k) {
                float val = (1.0f / (1.0f + __expf(-e[k]))) * so[k];
                e[k] = val;
                smax[k] = fmaxf(smax[k], val);
            }
        }

        // per position: one full 64B line = 4 back-to-back float4 stores
        #pragma unroll
        for (int k = 0; k < 4; ++k) {
            float* line = crow + (size_t)k * 3 * NCLS + c0;
            #pragma unroll
            for (int t = 0; t < 4; ++t) {
                const float* e0 = &v[4*t+0].x; const float* e1 = &v[4*t+1].x;
                const float* e2 = &v[4*t+2].x; const float* e3 = &v[4*t+3].x;
                *reinterpret_cast<float4*>(line + t * 4) =
                    make_float4(e0[k], e1[k], e2[k], e3[k]);
            }
        }
    }

    #pragma unroll
    for (int k = 0; k < 4; ++k)
        scores[(size_t)b * PP + (size_t)(s0 + k) * 3 + a] = smax[k];
}

extern "C" void kernel_launch(void* const* d_in, const int* in_sizes, int n_in,
                              void* d_out, int out_size, void* d_ws, size_t ws_size,
                              hipStream_t stream) {
    const float* in      = (const float*)d_in[0];
    const float* anchors = (const float*)d_in[1];

    float* boxes  = (float*)d_out;                       // B*P*4
    float* conf   = boxes + (size_t)BB * PP * 4;         // B*P*80
    float* scores = conf + (size_t)BB * PP * NCLS;       // B*P

    int total  = BB * NA * SQ;                           // 138,624
    int blocks = (total + 255) / 256;                    // 542
    yolo_decode_kernel<<<blocks, 256, 0, stream>>>(in, anchors, boxes, conf, scores);
}

// Round 4
// 106.251 us; speedup vs baseline: 1.8093x; 1.8093x over previous
//
#include <hip/hip_runtime.h>

// YOLO layer decode, MI355X. R4: LDS-staged transpose.
// Block = (b, a, 256-position tile). Class channels staged to LDS in 5 chunks
// of 16 channels x 256 positions via __builtin_amdgcn_global_load_lds (16B/lane,
// 1KB/wave/instr). Compute: 1 thread = 1 position, conflict-free LDS reads,
// full-64B-line conf stores with constant indexing (no scratch, per rule #20).

#define NCLS 80
#define NA   3
#define BB   32
#define WW   76
#define HH   76
#define WH   (WW*HH)          // 5776
#define PP   (WH*NA)          // 17328
#define TILE 256
#define NTILE ((WH + TILE - 1) / TILE)   // 23 (last tile has 144 valid)
#define CCH  16               // channels per staged chunk
#define NCHUNK (NCLS / CCH)   // 5

__global__ __launch_bounds__(256) void yolo_decode_kernel(
    const float* __restrict__ in,       // (B, 255, W, H)
    const float* __restrict__ anchors,  // (2, 3) flat: [d*3 + a]
    float* __restrict__ boxes,          // (B, P, 4)
    float* __restrict__ conf,           // (B, P, 80)
    float* __restrict__ scores)         // (B, P)
{
    __shared__ float chunk[CCH][TILE];  // 16 KB

    int bid  = blockIdx.x;
    int tile = bid % NTILE;
    int ba   = bid / NTILE;
    int a    = ba % NA;
    int b    = ba / NA;
    int s0   = tile * TILE;
    int i    = threadIdx.x;
    int valid = WH - s0; if (valid > TILE) valid = TILE;

    int lane = i & 63;
    int wv   = i >> 6;                  // wave id 0..3

    const float* plane0 = in + (size_t)(b * 255 + a * 85) * WH;

    // ---- head: 5 coalesced dword loads per thread ----
    int s  = s0 + i;
    int sc = s < WH ? s : WH - 1;       // clamped (tail threads compute garbage, never store)
    float tx = plane0[sc];
    float ty = plane0[(size_t)1 * WH + sc];
    float tw = plane0[(size_t)2 * WH + sc];
    float th = plane0[(size_t)3 * WH + sc];
    float to = plane0[(size_t)4 * WH + sc];

    float aw = anchors[a], ah = anchors[3 + a];
    int w = sc / HH;
    int h = sc - w * HH;
    float sx = 1.0f / (1.0f + __expf(-tx));
    float sy = 1.0f / (1.0f + __expf(-ty));
    float bx = (sx + (float)w) * (1.0f / WW);
    float by = (sy + (float)h) * (1.0f / HH);
    float bw = __expf(tw) * aw;
    float bh = __expf(th) * ah;

    int p = sc * 3 + a;
    if (i < valid) {
        float4 box = make_float4(bx - 0.5f * bw, by - 0.5f * bh,
                                 bx + 0.5f * bw, by + 0.5f * bh);
        *reinterpret_cast<float4*>(boxes + (size_t)(b * PP + p) * 4) = box;
    }

    float so   = 1.0f / (1.0f + __expf(-to));
    float smax = 0.0f;
    float* crow = conf + ((size_t)b * PP + p) * NCLS;

    // per-lane clamped source offset for staging (16B per lane)
    int soff = s0 + 4 * lane;
    if (soff > WH - 4) soff = WH - 4;   // only the last tile clamps

    for (int k = 0; k < NCHUNK; ++k) {
        // ---- stage 16 channels: wave wv owns rows wv*4 + r ----
        #pragma unroll
        for (int r = 0; r < 4; ++r) {
            int row = wv * 4 + r;
            int ch  = 5 + k * CCH + row;
            const float* gp = plane0 + (size_t)ch * WH + soff;
            __builtin_amdgcn_global_load_lds(
                (const __attribute__((address_space(1))) unsigned int*)gp,
                (__attribute__((address_space(3))) unsigned int*)&chunk[row][0],
                16, 0, 0);
        }
        __syncthreads();                 // drains vmcnt -> staged data visible

        // ---- compute: thread i = position s0+i ----
        float v[CCH];
        #pragma unroll
        for (int c = 0; c < CCH; ++c) {
            float t = chunk[c][i];
            float val = (1.0f / (1.0f + __expf(-t))) * so;
            v[c] = val;
            smax = fmaxf(smax, val);
        }
        if (i < valid) {
            #pragma unroll
            for (int t4 = 0; t4 < 4; ++t4) {
                *reinterpret_cast<float4*>(crow + k * CCH + t4 * 4) =
                    make_float4(v[4*t4+0], v[4*t4+1], v[4*t4+2], v[4*t4+3]);
            }
        }
        __syncthreads();                 // protect chunk buffer before next stage
    }

    if (i < valid)
        scores[(size_t)b * PP + p] = smax;
}

extern "C" void kernel_launch(void* const* d_in, const int* in_sizes, int n_in,
                              void* d_out, int out_size, void* d_ws, size_t ws_size,
                              hipStream_t stream) {
    const float* in      = (const float*)d_in[0];
    const float* anchors = (const float*)d_in[1];

    float* boxes  = (float*)d_out;                       // B*P*4
    float* conf   = boxes + (size_t)BB * PP * 4;         // B*P*80
    float* scores = conf + (size_t)BB * PP * NCLS;       // B*P

    int blocks = BB * NA * NTILE;                        // 2208
    yolo_decode_kernel<<<blocks, 256, 0, stream>>>(in, anchors, boxes, conf, scores);
}

// Round 5
// 82.062 us; speedup vs baseline: 2.3427x; 1.2948x over previous
//
#include <hip/hip_runtime.h>

// YOLO decode, MI355X. R5: fully coalesced OUTPUT stores.
// Block = (b, 64-position tile, all 3 anchors) so the block owns CONTIGUOUS
// output spans: conf 60KB, boxes 3KB, scores 768B. Class channels reg-staged
// TRANSPOSED into LDS cls[s][240] (row padded to 244 words for b128 align +
// bank spread). Conf threads compute exactly the 16B quad they store:
// ds_read_b128 in, lane-linear global_store_dwordx4 out (1KB/wave/instr).

#define NCLS 80
#define NA   3
#define BB   32
#define WW   76
#define HH   76
#define WH   (WW*HH)          // 5776
#define PP   (WH*NA)          // 17328
#define TS   64               // positions per tile
#define NTILE ((WH + TS - 1) / TS)   // 91 (last tile: 16 valid)
#define PROW 244              // padded LDS row stride (words)

__global__ __launch_bounds__(256, 2) void yolo_decode_kernel(
    const float* __restrict__ in,       // (B, 255, W, H)
    const float* __restrict__ anchors,  // (2, 3) flat: [d*3 + a]
    float* __restrict__ boxes,          // (B, P, 4)
    float* __restrict__ conf,           // (B, P, 80)
    float* __restrict__ scores)         // (B, P)
{
    __shared__ float  cls[TS * PROW];     // [s][a*80+c], 62464 B
    __shared__ float  so_buf[TS * NA];    // [p = s*3+a], 768 B
    __shared__ float4 box_buf[TS * NA];   // [p], 3072 B

    const int t    = threadIdx.x;
    const int bid  = blockIdx.x;
    const int tile = bid % NTILE;
    const int b    = bid / NTILE;
    const int s0   = tile * TS;
    int valid = WH - s0; if (valid > TS) valid = TS;

    const float* bplane = in + (size_t)b * 255 * WH;

    // ---- head loads (t<192): wave w handles anchor w, lanes = consecutive s ----
    int a_h  = t >> 6;           // 0..2 (wave 3 idle here)
    int sl_h = t & 63;
    int slc_h = sl_h < valid ? sl_h : valid - 1;
    float tx = 0.f, ty = 0.f, tw = 0.f, th = 0.f, to = 0.f;
    if (t < 192) {
        const float* hp = bplane + (size_t)(a_h * 85) * WH + s0 + slc_h;
        tx = hp[0];
        ty = hp[(size_t)1 * WH];
        tw = hp[(size_t)2 * WH];
        th = hp[(size_t)3 * WH];
        to = hp[(size_t)4 * WH];
    }

    // ---- stage 240 class channels transposed into LDS ----
    // unit = (ch-quad 0..59, sl 0..63); 3840 units, 15/thread.
    // Loads: lanes = consecutive sl of one plane -> fully coalesced dwords.
    // Write: one ds_write_b128 per unit into cls[sl][ch0..ch0+3].
    #pragma unroll
    for (int it = 0; it < 15; ++it) {
        int unit = it * 256 + t;
        int qch  = unit >> 6;          // 0..59
        int sl   = unit & 63;
        int slc  = sl < valid ? sl : valid - 1;
        int ch0  = qch * 4;            // 0..236 in a*80+c domain (never straddles a)
        int a    = ch0 / 80;
        int c0   = ch0 - a * 80;
        const float* gp = bplane + (size_t)(a * 85 + 5 + c0) * WH + s0 + slc;
        float v0 = gp[0];
        float v1 = gp[(size_t)1 * WH];
        float v2 = gp[(size_t)2 * WH];
        float v3 = gp[(size_t)3 * WH];
        *reinterpret_cast<float4*>(&cls[sl * PROW + ch0]) = make_float4(v0, v1, v2, v3);
    }

    // ---- head compute -> LDS bufs (t<192) ----
    if (t < 192) {
        int s = s0 + slc_h;
        int w = s / HH;
        int h = s - w * HH;
        float sx = 1.0f / (1.0f + __expf(-tx));
        float sy = 1.0f / (1.0f + __expf(-ty));
        float bx = (sx + (float)w) * (1.0f / WW);
        float by = (sy + (float)h) * (1.0f / HH);
        float bw = __expf(tw) * anchors[a_h];
        float bh = __expf(th) * anchors[3 + a_h];
        int p = slc_h * 3 + a_h;       // clamped dup writes store identical data
        box_buf[p] = make_float4(bx - 0.5f * bw, by - 0.5f * bh,
                                 bx + 0.5f * bw, by + 0.5f * bh);
        so_buf[p] = 1.0f / (1.0f + __expf(-to));
    }

    __syncthreads();

    // ---- conf: 3840 quads, 15/thread; stores lane-linear (1KB/wave/instr) ----
    size_t cbase = ((size_t)b * PP + (size_t)s0 * 3) * NCLS;   // word offset
    int vq = valid * 60;               // valid quads
    for (int it = 0; it < 15; ++it) {
        int q  = it * 256 + t;
        int p  = q / 20;
        int u  = q - p * 20;
        int sl = p / 3;
        int a  = p - sl * 3;
        float4 tv = *reinterpret_cast<const float4*>(&cls[sl * PROW + a * 80 + u * 4]);
        float so = so_buf[p];
        float4 o;
        o.x = (1.0f / (1.0f + __expf(-tv.x))) * so;
        o.y = (1.0f / (1.0f + __expf(-tv.y))) * so;
        o.z = (1.0f / (1.0f + __expf(-tv.z))) * so;
        o.w = (1.0f / (1.0f + __expf(-tv.w))) * so;
        if (q < vq)
            *reinterpret_cast<float4*>(conf + cbase + (size_t)q * 4) = o;
    }

    // ---- boxes + scores (t<192), lane-linear stores ----
    if (t < 192) {
        int p = t;
        float4 bq = box_buf[p];
        if (p < valid * 3)
            *reinterpret_cast<float4*>(boxes + ((size_t)b * PP + s0 * 3 + p) * 4) = bq;

        int sl = p / 3;
        int a  = p - sl * 3;
        float mx = -1e30f;
        #pragma unroll
        for (int c4 = 0; c4 < 20; ++c4) {
            float4 v = *reinterpret_cast<const float4*>(&cls[sl * PROW + a * 80 + c4 * 4]);
            mx = fmaxf(mx, fmaxf(fmaxf(v.x, v.y), fmaxf(v.z, v.w)));
        }
        float sc = so_buf[p] * (1.0f / (1.0f + __expf(-mx)));
        if (p < valid * 3)
            scores[(size_t)b * PP + s0 * 3 + p] = sc;
    }
}

extern "C" void kernel_launch(void* const* d_in, const int* in_sizes, int n_in,
                              void* d_out, int out_size, void* d_ws, size_t ws_size,
                              hipStream_t stream) {
    const float* in      = (const float*)d_in[0];
    const float* anchors = (const float*)d_in[1];

    float* boxes  = (float*)d_out;                       // B*P*4
    float* conf   = boxes + (size_t)BB * PP * 4;         // B*P*80
    float* scores = conf + (size_t)BB * PP * NCLS;       // B*P

    int blocks = BB * NTILE;                             // 2912
    yolo_decode_kernel<<<blocks, 256, 0, stream>>>(in, anchors, boxes, conf, scores);
}